// Round 7
// baseline (243.929 us; speedup 1.0000x reference)
//
#include <hip/hip_runtime.h>
#include <stdint.h>

// CombinedLoss: weighted CE + dice + focal + connected-component separation.
// B=16, C=3, H=W=512. Output: single f32 scalar.
//
// R6 resubmit (R6 bench timed out before running; source unchanged):
// labels stored as ushort tile-local root idx (lab16, 0xFFFF=bg);
// parent+conf fused in int2 pc[] per mask, initialized ONLY at root pixels;
// k_count deleted (SENT-transitions counted exactly-once inside k_scatter);
// k_reduce + Accum + memset deleted (folded into k_final). 5 dispatches:
//   k_main    : fused softmax losses -> Partial[1024]; bit-packed fg masks
//   k_local   : per 64x64 tile run-based CC in LDS -> lab16 + pc[root]={root,0}
//   k_border  : global unite on pc.x for tile-crossing edges only
//   k_scatter : stream lab16; overlap px: chase both roots; conf CAS on pc.y
//               with exact transition counting -> penpart[block]
//   k_final   : 1 block reduces Partials + penpart, combines into d_out[0]

#define NB 16
#define NC 3
#define HH 512
#define WW 512
#define HW (HH * WW)          // 262144
#define NPIX (NB * HW)        // 4194304
#define LOG2_HW 18
#define IGNORE_IDX 255
#define SCALE_IDX 2
#define SENT (-1)             // conflict sentinel: >=2 distinct neighbor roots
#define BG16 0xFFFF

typedef unsigned long long u64;

struct Partial {           // 96 B
  double d[9];             // ce_num, ce_den, focal, sp0..2, it0..2
  unsigned int u[6];       // c0, c1, c2, valid, tcnt, pcnt
};

__device__ __forceinline__ double wredd(double v) {
#pragma unroll
  for (int o = 32; o > 0; o >>= 1) v += __shfl_down(v, o, 64);
  return v;
}
__device__ __forceinline__ unsigned int wredu(unsigned int v) {
#pragma unroll
  for (int o = 32; o > 0; o >>= 1) v += __shfl_down(v, o, 64);
  return v;
}

// ---------- fused pointwise losses + mask generation ----------
__global__ __launch_bounds__(256) void k_main(
    const float* __restrict__ pred, const int* __restrict__ tgt,
    const float* __restrict__ cw, Partial* __restrict__ part,
    u64* __restrict__ tmask, u64* __restrict__ pmask) {
  const int bid = blockIdx.x;
  const int b = bid >> 6;        // 64 blocks per batch image
  const int chunk = bid & 63;    // 4096 pixels per block, 16 iters of 256
  const int tid = threadIdx.x;
  const float w0 = cw[0], w1 = cw[1], w2 = cw[2];
  const float* __restrict__ pb = pred + (size_t)b * NC * HW;

  float ce_num = 0.f, ce_den = 0.f, focal = 0.f;
  float sp0 = 0.f, sp1 = 0.f, sp2 = 0.f, it0 = 0.f, it1 = 0.f, it2 = 0.f;
  unsigned int c0 = 0, c1 = 0, c2 = 0, vc = 0, tc_cnt = 0, pc_cnt = 0;

#pragma unroll 1
  for (int k = 0; k < 16; ++k) {
    const int i = (chunk << 12) + (k << 8) + tid;  // local pixel in image
    const int gp = (b << LOG2_HW) + i;
    const float x0 = pb[i];
    const float x1 = pb[i + HW];
    const float x2 = pb[i + 2 * HW];
    const int t = tgt[gp];

    // log_softmax, jax style: (x - max) - log(sum(exp(x - max)))
    const float m = fmaxf(fmaxf(x0, x1), x2);
    const float e0 = expf(x0 - m), e1 = expf(x1 - m), e2 = expf(x2 - m);
    const float s = e0 + e1 + e2;
    const float ls = logf(s);
    const float inv = 1.0f / s;
    const float p0 = e0 * inv, p1 = e1 * inv, p2 = e2 * inv;

    sp0 += p0; sp1 += p1; sp2 += p2;

    const int tc = (t < 0) ? 0 : ((t > NC - 1) ? NC - 1 : t);
    const float xt = (tc == 0) ? x0 : ((tc == 1) ? x1 : x2);
    const float lpt = (xt - m) - ls;
    const float pt  = (tc == 0) ? p0 : ((tc == 1) ? p1 : p2);
    const float cwt = (tc == 0) ? w0 : ((tc == 1) ? w1 : w2);
    const float valid = (t != IGNORE_IDX) ? 1.0f : 0.0f;
    const float wv = cwt * valid;

    ce_num += wv * (-lpt);
    ce_den += wv;
    const float om = 1.0f - pt;
    focal += cwt * om * om * (-lpt) * valid;
    vc += (t != IGNORE_IDX) ? 1u : 0u;

    if (t >= 0 && t < NC) {  // one_hot(out-of-range) == 0
      if (t == 0)      { it0 += p0; c0++; }
      else if (t == 1) { it1 += p1; c1++; }
      else             { it2 += p2; c2++; }
    }

    const bool tb = (t == SCALE_IDX);
    const float p2soft = e2 / s;            // IEEE div: threshold identical to R5
    const bool pbit = (p2soft > 0.5f);
    const u64 mt = __ballot(tb);
    const u64 mp = __ballot(pbit);
    if ((tid & 63) == 0) {
      tmask[gp >> 6] = mt;
      pmask[gp >> 6] = mp;
    }
    tc_cnt += tb ? 1u : 0u;
    pc_cnt += pbit ? 1u : 0u;
  }

  // wave -> block reduction; thread0 stores one Partial (NO atomics)
  __shared__ double sd[4][9];
  __shared__ unsigned int si[4][6];
  const int wvid = tid >> 6, ln = tid & 63;
  const double r0 = wredd((double)ce_num), r1 = wredd((double)ce_den),
               r2 = wredd((double)focal),
               r3 = wredd((double)sp0), r4 = wredd((double)sp1),
               r5 = wredd((double)sp2),
               r6 = wredd((double)it0), r7 = wredd((double)it1),
               r8 = wredd((double)it2);
  const unsigned int u0 = wredu(c0), u1 = wredu(c1), u2 = wredu(c2),
                     u3 = wredu(vc), u4 = wredu(tc_cnt), u5 = wredu(pc_cnt);
  if (ln == 0) {
    sd[wvid][0] = r0; sd[wvid][1] = r1; sd[wvid][2] = r2;
    sd[wvid][3] = r3; sd[wvid][4] = r4; sd[wvid][5] = r5;
    sd[wvid][6] = r6; sd[wvid][7] = r7; sd[wvid][8] = r8;
    si[wvid][0] = u0; si[wvid][1] = u1; si[wvid][2] = u2;
    si[wvid][3] = u3; si[wvid][4] = u4; si[wvid][5] = u5;
  }
  __syncthreads();
  if (tid == 0) {
    Partial p;
    for (int q = 0; q < 9; ++q) p.d[q] = sd[0][q] + sd[1][q] + sd[2][q] + sd[3][q];
    for (int q = 0; q < 6; ++q) p.u[q] = si[0][q] + si[1][q] + si[2][q] + si[3][q];
    part[bid] = p;
  }
}

// ---------- LDS union-find helpers ----------
__device__ __forceinline__ int find_lds(volatile int* par, int x) {
  int p = par[x];
  while (p != x) { x = p; p = par[x]; }
  return x;
}
__device__ __forceinline__ void unite_lds(int* par, int a, int b) {
  int la = find_lds(par, a);
  int lb = find_lds(par, b);
  while (la != lb) {
    if (la < lb) { int t = la; la = lb; lb = t; }  // la > lb
    const int old = atomicMin(&par[la], lb);
    if (old == la) break;
    la = old;
  }
}

// one block = one (image, mask, 64x64 tile); run-based CC in LDS.
// Writes lab16 (ushort local-root idx, BG16 for bg) and pc[root]={root, 0}.
__global__ __launch_bounds__(256) void k_local(
    const u64* __restrict__ tmask, const u64* __restrict__ pmask,
    ushort* __restrict__ tlab16, ushort* __restrict__ plab16,
    int2* __restrict__ pc_t, int2* __restrict__ pc_p) {
  const int idx = blockIdx.x;
  const int img = idx >> 7;
  const int rest = idx & 127;
  const int maskid = rest >> 6;
  const int tile = rest & 63;
  const int ty = tile >> 3, tx = tile & 7;
  const u64* __restrict__ mg = (maskid ? pmask : tmask) + (size_t)img * (HW / 64);
  ushort* __restrict__ lab = (maskid ? plab16 : tlab16) + (size_t)img * HW;
  int2* __restrict__ pc   = (maskid ? pc_p : pc_t) + (size_t)img * HW;
  const int tid = threadIdx.x;
  const int lane = tid & 63, wv = tid >> 6;

  __shared__ int par[4096];
  __shared__ u64 mw[64];
  if (tid < 64) mw[tid] = mg[(ty * 64 + tid) * 8 + tx];  // tile row = 1 u64 word
  __syncthreads();

  // Phase A: init with run-start labels (merges ALL horizontal edges for free)
#pragma unroll 1
  for (int k = 0; k < 16; ++k) {
    const int y = (k << 2) + wv;             // wave wv owns rows wv, wv+4, ...
    const u64 w = mw[y];
    int v = -1;
    if ((w >> lane) & 1ull) {
      const u64 sa = w & ~(w << 1);                       // run-start bits
      const u64 le = sa & (~0ull >> (63 - lane));         // starts at <= lane
      v = (y << 6) + (63 - __clzll(le));                  // my run's start
    }
    par[(y << 6) + lane] = v;
  }
  __syncthreads();

  // Phase B: run-start lanes unite with each distinct above-run overlapping
  // the window [runstart-1, runend+1] (covers N/NW/NE, deduped per run pair).
#pragma unroll 1
  for (int k = 0; k < 16; ++k) {
    const int y = (k << 2) + wv;
    if (y == 0) continue;
    const u64 w = mw[y];
    if (!((w >> lane) & 1ull)) continue;
    if (lane > 0 && ((w >> (lane - 1)) & 1ull)) continue;  // not a run start
    const u64 z = w >> lane;
    const u64 crun = (z & ~(z + 1)) << lane;               // bits of my run
    const u64 win = crun | (crun << 1) | (crun >> 1);
    const u64 a = mw[y - 1];
    u64 aw = a & win;
    const u64 sa = a & ~(a << 1);
    const int me = (y << 6) + lane;
    while (aw) {
      const int p = (int)(__ffsll((long long)aw) - 1);
      const u64 le = sa & (~0ull >> (63 - p));
      const int rs = 63 - __clzll(le);                     // above run's start
      unite_lds(par, me, ((y - 1) << 6) + rs);
      const u64 za = a >> p;
      aw &= ~((za & ~(za + 1)) << p);                      // clear that run
    }
  }
  __syncthreads();

  // Phase C: write lab16 (4 px/thread, ushort4) + pc init at roots only
#pragma unroll 1
  for (int k = 0; k < 4; ++k) {
    const int lbase = (k << 10) + (tid << 2);              // 4 consecutive px
    const int gy = (ty << 6) + (lbase >> 6);
    const int gx = (tx << 6) + (lbase & 63);
    const int gbase = gy * WW + gx;
    ushort v[4];
#pragma unroll
    for (int j = 0; j < 4; ++j) {
      const int li = lbase + j;
      int r = par[li];
      ushort out = BG16;
      if (r >= 0) {
        const bool isroot = (r == li);
        int p = par[r];
        while (p != r) { r = p; p = par[r]; }  // static after barrier
        out = (ushort)r;
        if (isroot) pc[gbase + j] = make_int2(gbase + j, 0);
      }
      v[j] = out;
    }
    *reinterpret_cast<ushort4*>(&lab[gbase]) =
        make_ushort4(v[0], v[1], v[2], v[3]);
  }
}

// ---------- global union-find on pc.x (border edges only) ----------
__device__ __forceinline__ int pc_par(int2* pc, int x) {
  // bypass per-CU L1 during concurrent merge: peers' atomicMin land in L2
  return __hip_atomic_load(&pc[x].x, __ATOMIC_RELAXED, __HIP_MEMORY_SCOPE_AGENT);
}
__device__ __forceinline__ int findroot_pc(int2* pc, int x) {
  int p = pc_par(pc, x);
  while (p != x) { x = p; p = pc_par(pc, x); }
  return x;
}
__device__ __forceinline__ void unite_pc(int2* pc, int a, int b) {
  int la = findroot_pc(pc, a);
  int lb = findroot_pc(pc, b);
  while (la != lb) {
    if (la < lb) { int t = la; la = lb; lb = t; }
    const int old = atomicMin(&pc[la].x, lb);
    if (old == la) break;
    la = old;
  }
}

// global pixel idx of the tile-root encoded by (pixel's tile, local idx l)
__device__ __forceinline__ int decode_root(int ty, int tx, int l) {
  return ((ty << 6) + (l >> 6)) * WW + (tx << 6) + (l & 63);
}

// 21 lines per (img, mask): 7 horiz rows y=64k; 7 cols x=64k; 7 cols x=64k-1
__global__ __launch_bounds__(256) void k_border(
    const ushort* __restrict__ tlab16, const ushort* __restrict__ plab16,
    int2* __restrict__ pc_t, int2* __restrict__ pc_p) {
  const int t = blockIdx.x * 256 + threadIdx.x;  // 344064 total
  const int pos = t & 511;
  const int rest = t >> 9;          // 0..671
  const int line = rest % 21;
  const int rest2 = rest / 21;      // 0..31
  const int maskid = rest2 & 1;
  const int img = rest2 >> 1;
  const ushort* __restrict__ lab = (maskid ? plab16 : tlab16) + (size_t)img * HW;
  int2* __restrict__ pc = (maskid ? pc_p : pc_t) + (size_t)img * HW;

  if (line < 7) {                        // horizontal border row y = 64*(line+1)
    const int y = (line + 1) << 6;
    const int i = y * WW + pos;
    const ushort li = lab[i];
    if (li == BG16) return;
    const int ty = line + 1, tx = pos >> 6;
    const int gi = decode_root(ty, tx, li);
    const ushort ln_ = lab[i - WW];
    if (ln_ != BG16) unite_pc(pc, gi, decode_root(line, tx, ln_));               // N
    if (pos > 0) {
      const ushort lw = lab[i - WW - 1];
      if (lw != BG16) unite_pc(pc, gi, decode_root(line, (pos - 1) >> 6, lw));   // NW
    }
    if (pos < WW - 1) {
      const ushort le = lab[i - WW + 1];
      if (le != BG16) unite_pc(pc, gi, decode_root(line, (pos + 1) >> 6, le));   // NE
    }
  } else if (line < 14) {                // vertical border, left col x = 64*(line-6)
    const int x = (line - 6) << 6;
    const int i = pos * WW + x;
    const ushort li = lab[i];
    if (li == BG16) return;
    const int ty = pos >> 6, tx = line - 6;
    const int gi = decode_root(ty, tx, li);
    const ushort lw = lab[i - 1];
    if (lw != BG16) unite_pc(pc, gi, decode_root(ty, tx - 1, lw));               // W
    if (pos > 0) {
      const ushort ld = lab[i - WW - 1];
      if (ld != BG16) unite_pc(pc, gi, decode_root((pos - 1) >> 6, tx - 1, ld)); // NW
    }
  } else {                               // vertical border, right col x = 64*(line-13)-1
    if (pos == 0) return;
    const int x = ((line - 13) << 6) - 1;
    const int i = pos * WW + x;
    const ushort li = lab[i];
    if (li == BG16) return;
    const int ty = pos >> 6, tx = x >> 6;
    const int gi = decode_root(ty, tx, li);
    const ushort le = lab[i - WW + 1];
    if (le != BG16) unite_pc(pc, gi, decode_root((pos - 1) >> 6, tx + 1, le));   // NE
  }
}

// read-only chase with path compression (forest static after k_border; all
// compress writers store the same final root -> benign race)
__device__ __forceinline__ int chase_pc(int2* __restrict__ pc, int g) {
  int r = pc[g].x;
  if (r == g) return r;
  int p = pc[r].x;
  while (p != r) { r = p; p = pc[r].x; }
  pc[g].x = r;
  return r;
}

// monotone conf slot on pc.y: 0 -> val+1 -> SENT. Returns 1 iff THIS call
// performed the transition to SENT (exactly-once counting).
__device__ __forceinline__ int conf_update(int2* __restrict__ pc, int key, int val) {
  const int tag = val + 1;  // val < 2^18 -> tag > 0, != SENT
  const int old = atomicCAS(&pc[key].y, 0, tag);
  if (old == 0 || old == tag || old == SENT) return 0;
  const int prev = atomicExch(&pc[key].y, SENT);  // second distinct tag
  return (prev != SENT) ? 1 : 0;
}

// 4 px/thread; activity from lab16 itself (no mask reads); streams lab16.
__global__ __launch_bounds__(256) void k_scatter(
    const ushort* __restrict__ tlab16, const ushort* __restrict__ plab16,
    int2* __restrict__ pc_t, int2* __restrict__ pc_p,
    int* __restrict__ penpart) {
  const int gt4 = blockIdx.x * 256 + threadIdx.x;  // over NPIX/4
  const int img = gt4 >> (LOG2_HW - 2);
  const int i0 = (gt4 & ((HW >> 2) - 1)) << 2;     // pixel in image
  const size_t ibase = (size_t)img * HW;
  const ushort4 t4 = *reinterpret_cast<const ushort4*>(&tlab16[ibase + i0]);
  const ushort4 p4 = *reinterpret_cast<const ushort4*>(&plab16[ibase + i0]);
  int2* __restrict__ pct = pc_t + ibase;
  int2* __restrict__ pcp = pc_p + ibase;
  const ushort tl[4] = {t4.x, t4.y, t4.z, t4.w};
  const ushort pl[4] = {p4.x, p4.y, p4.z, p4.w};

  int cnt = 0;
  const int y = i0 >> 9, ty = y >> 6, txb = (i0 & 511) >> 6;  // 4 px same tile
#pragma unroll
  for (int j = 0; j < 4; ++j) {
    if (tl[j] != BG16 && pl[j] != BG16) {
      const int gt_root = decode_root(ty, txb, tl[j]);
      const int gp_root = decode_root(ty, txb, pl[j]);
      const int rt = chase_pc(pct, gt_root);
      const int rp = chase_pc(pcp, gp_root);
      cnt += conf_update(pct, rt, rp);
      cnt += conf_update(pcp, rp, rt);
    }
  }

  const int tid = threadIdx.x, ln = tid & 63, wv = tid >> 6;
#pragma unroll
  for (int o = 32; o > 0; o >>= 1) cnt += __shfl_down(cnt, o, 64);
  __shared__ int s4[4];
  if (ln == 0) s4[wv] = cnt;
  __syncthreads();
  if (tid == 0) penpart[blockIdx.x] = s4[0] + s4[1] + s4[2] + s4[3];  // NO atomics
}

// 1 block: wave w reduces image w's 64 Partials + 256 penpart entries;
// thread 0 combines everything into the scalar output.
__global__ __launch_bounds__(1024) void k_final(
    const Partial* __restrict__ part, const int* __restrict__ penpart,
    float* __restrict__ out) {
  const int tid = threadIdx.x, w = tid >> 6, l = tid & 63;
  const Partial p = part[w * 64 + l];
  double d[9];
  unsigned int u[6];
#pragma unroll
  for (int q = 0; q < 9; ++q) d[q] = wredd(p.d[q]);
#pragma unroll
  for (int q = 0; q < 6; ++q) u[q] = wredu(p.u[q]);

  int s = 0;
#pragma unroll
  for (int k = 0; k < 4; ++k) s += penpart[(w << 8) + (k << 6) + l];
#pragma unroll
  for (int o = 32; o > 0; o >>= 1) s += __shfl_down(s, o, 64);

  __shared__ double imgd[16][9];
  __shared__ unsigned int imgu[16][6];
  __shared__ int pens[16];
  if (l == 0) {
#pragma unroll
    for (int q = 0; q < 9; ++q) imgd[w][q] = d[q];
#pragma unroll
    for (int q = 0; q < 6; ++q) imgu[w][q] = u[q];
    pens[w] = s;
  }
  __syncthreads();
  if (tid != 0) return;

  double a0 = 0, a1 = 0, a2 = 0;
  unsigned long long av = 0;
  for (int q = 0; q < 16; ++q) {
    a0 += imgd[q][0]; a1 += imgd[q][1]; a2 += imgd[q][2];
    av += (unsigned long long)imgu[q][3];
  }
  const double ce = a0 / a1;
  double dsum = 0.0;
  for (int b = 0; b < NB; ++b)
    for (int c = 0; c < NC; ++c) {
      const double un = imgd[b][3 + c] + (double)imgu[b][c];
      dsum += (2.0 * imgd[b][6 + c] + 1e-6) / (un + 1e-6);
    }
  const double dice = 1.0 - dsum / (double)(NB * NC);
  const double focal = a2 / ((double)av + 1e-6);
  long long tt = 0, pp = 0;
  int nv = 0;
  double pensum = 0.0;
  for (int b = 0; b < NB; ++b) {
    tt += imgu[b][4];
    pp += imgu[b][5];
    if (imgu[b][4] > 0) { nv++; pensum += (double)pens[b]; }
  }
  double pen = 0.0;
  if (nv > 0) pen = pensum / fmax((double)nv * 2.0, 1.0);
  const double sep = (tt > 0 && pp > 0) ? 1.0 /*SEP_PW*/ * pen : 0.0;
  *out = (float)(ce + 0.5 * dice + 0.5 * focal + 0.3 * sep);
}

extern "C" void kernel_launch(void* const* d_in, const int* in_sizes, int n_in,
                              void* d_out, int out_size, void* d_ws, size_t ws_size,
                              hipStream_t stream) {
  (void)in_sizes; (void)n_in; (void)out_size; (void)ws_size;
  const float* pred = (const float*)d_in[0];
  const int* tgt = (const int*)d_in[1];
  const float* cw = (const float*)d_in[2];
  float* out = (float*)d_out;

  char* ws = (char*)d_ws;
  size_t off = 0;
  Partial* part = (Partial*)(ws + off); off += sizeof(Partial) * NB * 64;  // 96 KB
  u64* tmask = (u64*)(ws + off); off += NPIX / 8;                          // 512 KB
  u64* pmask = (u64*)(ws + off); off += NPIX / 8;
  ushort* tlab16 = (ushort*)(ws + off); off += (size_t)NPIX * 2;           // 8 MB
  ushort* plab16 = (ushort*)(ws + off); off += (size_t)NPIX * 2;
  int2* pc_t = (int2*)(ws + off); off += (size_t)NPIX * 8;                 // 33.5 MB
  int2* pc_p = (int2*)(ws + off); off += (size_t)NPIX * 8;
  int* penpart = (int*)(ws + off); off += (size_t)(NPIX / 1024) * 4;       // 16 KB
  // total ~84.3 MiB (R1 proved ws_size >= ~97 MiB)

  k_main<<<NB * 64, 256, 0, stream>>>(pred, tgt, cw, part, tmask, pmask);
  k_local<<<NB * 64 * 2, 256, 0, stream>>>(tmask, pmask, tlab16, plab16, pc_t, pc_p);
  k_border<<<(NB * 2 * 21 * 512) / 256, 256, 0, stream>>>(tlab16, plab16, pc_t, pc_p);
  k_scatter<<<NPIX / 1024, 256, 0, stream>>>(tlab16, plab16, pc_t, pc_p, penpart);
  k_final<<<1, 1024, 0, stream>>>(part, penpart, out);
}